// Round 5
// baseline (555.899 us; speedup 1.0000x reference)
//
#include <hip/hip_runtime.h>
#include <hip/hip_bf16.h>

// Output buffer is FLOAT32-uniform (tuple concat promotes bf16+f32 -> f32):
// final_out [B,512] stored as bf16-rounded f32, guide_loss f32 @ B*512,
// sel_emb [B,128] f32 @ B*512+1.
// B=16384, E=8, D_IN=900, D_MODEL=512, D_SEL=128, top-2.

#define B_ROWS 16384
#define DIN 900
#define DM 512
#define DSEL 128
#define KP 928          // 900 padded to 29*32
#define NKS 29
#define MAXT 192
#define EPSF 1e-9f

#define OUT_GUIDE (B_ROWS*DM)
#define OUT_SEL   (B_ROWS*DM + 1)

// workspace layout (bytes); total ~7.9 MB
#define WS_COUNTS 0                      // int[64]
#define WS_COUNT2 256                    // int[64]
#define WS_SACC   512                    // float
#define WS_NT     576                    // int
#define WS_OFF    640                    // int[64]
#define WS_ENT    1024                   // int4[448]
#define WS_PID    8192                   // int[B]
#define WS_GATEB  73728                  // float2[B]
#define WS_ROWSS  204800                 // int[B]
#define WS_WT     270336                 // ushort[E*DM*KP] (7.6 MB)

typedef __attribute__((ext_vector_type(8))) short short8;
typedef __attribute__((ext_vector_type(8))) unsigned short ushort8;
typedef __attribute__((ext_vector_type(4))) float floatx4;

__device__ inline unsigned short f2bf(float v){
  union { __hip_bfloat16 h; unsigned short u; } c;
  c.h = __float2bfloat16(v);
  return c.u;
}
__device__ inline float bf2f(unsigned short u){
  union { unsigned int i; float f; } c;
  c.i = ((unsigned int)u) << 16;
  return c.f;
}

// ---- W f32 [E,900,512] -> bf16 transposed [E,512,928] (K zero-padded) ----
__global__ __launch_bounds__(256) void cvtw_k(const float* __restrict__ W,
                                              unsigned short* __restrict__ wt){
  __shared__ unsigned short tl[64][65];
  int kt = blockIdx.x, ntb = blockIdx.y, e = blockIdx.z;
  int c = threadIdx.x & 63, q = threadIdx.x >> 6;
  for (int i = 0; i < 16; i++){
    int kl = q + i*4;
    int k = kt*64 + kl;
    float v = (k < DIN) ? W[((size_t)e*DIN + k)*DM + ntb*64 + c] : 0.f;
    tl[kl][c] = f2bf(v);
  }
  __syncthreads();
  for (int i = 0; i < 16; i++){
    int nl = q + i*4;
    int k = kt*64 + c;
    if (k < KP)
      wt[((size_t)e*DM + ntb*64 + nl)*KP + k] = tl[c][nl];
  }
}

// ---- gating: softmax, sel-embedding (f32 out), top-2 gates, pair counting ----
__global__ __launch_bounds__(256) void gating_k(const float* __restrict__ logits,
                                                const int* __restrict__ masks,
                                                const float* __restrict__ sel,
                                                int* __restrict__ counts,
                                                float* __restrict__ sacc,
                                                int* __restrict__ pidv,
                                                float2* __restrict__ gatesb,
                                                float* __restrict__ out){
  int wid = threadIdx.x >> 6, lane = threadIdx.x & 63;
  int b = blockIdx.x*4 + wid;      // one wave per row
  float raw[8]; int mk[8];
  for (int e = 0; e < 8; e++){ raw[e] = logits[b*8+e]; mk[e] = masks[b*8+e]; }
  float mx = raw[0];
  for (int e = 1; e < 8; e++) mx = fmaxf(mx, raw[e]);
  float Z = 0.f;
  for (int e = 0; e < 8; e++){ raw[e] = expf(raw[e]-mx); Z += raw[e]; }
  float invZ = 1.f/Z;
  float act[8], ina[8]; float srm = 0.f, isum = 0.f;
  for (int e = 0; e < 8; e++){
    raw[e] *= invZ;
    if (mk[e] == 1){ act[e] = raw[e]; ina[e] = 0.f; srm += raw[e]; }
    else           { act[e] = 0.f;    ina[e] = raw[e]; isum += raw[e]; }
  }
  // top-2 (strict > replicates top_k lowest-index-first tie-break)
  float v1 = -1.f, v2 = -1.f; int e1 = 0, e2 = 0;
  for (int e = 0; e < 8; e++){
    float a = act[e];
    if (a > v1){ v2 = v1; e2 = e1; v1 = a; e1 = e; }
    else if (a > v2){ v2 = a; e2 = e; }
  }
  float den = v1 + v2 + EPSF;
  float g1 = v1/den, g2 = v2/den;
  int lo, hi; float gl, gh;
  if (e1 < e2){ lo = e1; hi = e2; gl = g1; gh = g2; }
  else        { lo = e2; hi = e1; gl = g2; gh = g1; }
  int pid = lo*8 + hi;
  // inactive-mixture selection embedding: dims lane, lane+64 (raw f32 out)
  float invI = 1.f/(isum + EPSF);
  const float* sb = sel + (size_t)b*(8*DSEL);
  float a0 = 0.f, a1 = 0.f;
  for (int e = 0; e < 8; e++){
    float w = ina[e]*invI;
    a0 += w * sb[e*DSEL + lane];
    a1 += w * sb[e*DSEL + lane + 64];
  }
  out[OUT_SEL + (size_t)b*DSEL + lane]      = a0;
  out[OUT_SEL + (size_t)b*DSEL + lane + 64] = a1;
  if (lane == 0){
    pidv[b] = pid;
    gatesb[b] = make_float2(gl, gh);
    atomicAdd(&counts[pid], 1);
    atomicAdd(sacc, srm);
  }
}

// ---- worklist: prefix offsets, tile entries, guide loss (f32 out) ----
__global__ void worklist_k(const int* __restrict__ counts, int* __restrict__ off,
                           int* __restrict__ ntp, int4* __restrict__ entries,
                           const float* __restrict__ sacc,
                           float* __restrict__ out){
  if (threadIdx.x == 0){
    float s = *sacc * (1.f/B_ROWS);
    float d = 1.f - s;
    out[OUT_GUIDE] = d*d;
    int nt = 0, run = 0;
    for (int p = 0; p < 64; ++p){
      int c = counts[p];
      off[p] = run;
      int elo = p >> 3, ehi = p & 7;
      for (int j = 0; j < c; j += 128){
        int nr = c - j; if (nr > 128) nr = 128;
        entries[nt] = make_int4(elo, ehi, run + j, nr);
        ++nt;
      }
      run += c;
    }
    *ntp = nt;
  }
}

// ---- scatter rows into dense per-pair segments ----
__global__ __launch_bounds__(256) void scatter_k(const int* __restrict__ pidv,
                                                 const int* __restrict__ off,
                                                 int* __restrict__ count2,
                                                 int* __restrict__ rows_s){
  int b = blockIdx.x*256 + threadIdx.x;
  int p = pidv[b];
  int pos = atomicAdd(&count2[p], 1);
  rows_s[off[p] + pos] = b;
}

// ---- grouped GEMM: 128-row pair tile x 128 cols, bf16 MFMA, gates folded into x ----
__global__ __launch_bounds__(256) void gemm_k(const float* __restrict__ xf,
                                              const unsigned short* __restrict__ wt,
                                              const float* __restrict__ bias,
                                              const int* __restrict__ ntp,
                                              const int4* __restrict__ entries,
                                              const int* __restrict__ rows_s,
                                              const float2* __restrict__ gatesb,
                                              float* __restrict__ out){
  int tile = blockIdx.x;
  if (tile >= *ntp) return;
  int4 ent = entries[tile];
  int elo = ent.x, ehi = ent.y, start = ent.z, nrows = ent.w;

  __shared__ __align__(16) unsigned short xs[128*40];  // stride 40: 2-way-free banks
  __shared__ int   gidx_s[128];
  __shared__ float glo_s[128];
  __shared__ float ghi_s[128];

  int t = threadIdx.x;
  if (t < 128){
    if (t < nrows){
      int g = rows_s[start + t];
      gidx_s[t] = g;
      float2 gg = gatesb[g];
      glo_s[t] = gg.x; ghi_s[t] = gg.y;
    } else { gidx_s[t] = -1; glo_s[t] = 0.f; ghi_s[t] = 0.f; }
  }
  __syncthreads();

  int lane = t & 63, wid = t >> 6;
  int wrow = wid >> 1, wcol = wid & 1;
  int quad = lane >> 4, l16 = lane & 15;
  int colbase = blockIdx.y*128 + wcol*64;

  int srow = t >> 1, skc = t & 1;
  int sg = gidx_s[srow];
  const float* xrow = xf + (size_t)(sg >= 0 ? sg : 0)*DIN + skc*16;

  floatx4 acc[4][4];
  for (int i = 0; i < 4; i++) for (int j = 0; j < 4; j++)
    for (int r = 0; r < 4; r++) acc[i][j][r] = 0.f;

  for (int pass = 0; pass < 2; ++pass){
    int e = pass ? ehi : elo;
    float g = (sg >= 0) ? (pass ? ghi_s[srow] : glo_s[srow]) : 0.f;
    const unsigned short* wb = wt + (size_t)e*DM*KP;
    for (int ks = 0; ks < NKS; ++ks){
      __syncthreads();
      // stage gate-scaled bf16 x-tile from f32 input: thread (srow,skc) covers 16 k's
      ushort8 y0, y1;
      if (ks < 28){
        const float4* p = (const float4*)(xrow + ks*32);
        float4 a0 = p[0], a1 = p[1], a2 = p[2], a3 = p[3];
        y0[0]=f2bf(g*a0.x); y0[1]=f2bf(g*a0.y); y0[2]=f2bf(g*a0.z); y0[3]=f2bf(g*a0.w);
        y0[4]=f2bf(g*a1.x); y0[5]=f2bf(g*a1.y); y0[6]=f2bf(g*a1.z); y0[7]=f2bf(g*a1.w);
        y1[0]=f2bf(g*a2.x); y1[1]=f2bf(g*a2.y); y1[2]=f2bf(g*a2.z); y1[3]=f2bf(g*a2.w);
        y1[4]=f2bf(g*a3.x); y1[5]=f2bf(g*a3.y); y1[6]=f2bf(g*a3.z); y1[7]=f2bf(g*a3.w);
      } else {
        for (int j = 0; j < 8; j++){
          int k = ks*32 + skc*16 + j;
          float v = (k < DIN) ? xrow[ks*32 + j] : 0.f;
          y0[j] = f2bf(g*v);
        }
        for (int j = 0; j < 8; j++){
          int k = ks*32 + skc*16 + 8 + j;
          float v = (k < DIN) ? xrow[ks*32 + 8 + j] : 0.f;
          y1[j] = f2bf(g*v);
        }
      }
      *((ushort8*)&xs[srow*40 + skc*16])     = y0;
      *((ushort8*)&xs[srow*40 + skc*16 + 8]) = y1;
      __syncthreads();
      short8 af[4];
      for (int mt = 0; mt < 4; ++mt)
        af[mt] = *((const short8*)&xs[(wrow*64 + mt*16 + l16)*40 + quad*8]);
      for (int nt = 0; nt < 4; ++nt){
        int n = colbase + nt*16 + l16;
        short8 bfr = *((const short8*)(wb + (size_t)n*KP + ks*32 + quad*8));
        for (int mt = 0; mt < 4; ++mt)
          acc[mt][nt] = __builtin_amdgcn_mfma_f32_16x16x32_bf16(af[mt], bfr, acc[mt][nt], 0, 0, 0);
      }
    }
  }
  // epilogue: C layout col=lane&15, row=quad*4+reg; add gated biases,
  // store bf16-rounded value widened to f32 (matches ref astype(bf16))
  for (int nt = 0; nt < 4; ++nt){
    int n = colbase + nt*16 + l16;
    float blo = bias[elo*DM + n];
    float bhi = bias[ehi*DM + n];
    for (int mt = 0; mt < 4; ++mt){
      int rl = wrow*64 + mt*16 + quad*4;
      for (int r = 0; r < 4; ++r){
        int rr = rl + r;
        int grow = gidx_s[rr];
        if (grow >= 0){
          float v = acc[mt][nt][r] + glo_s[rr]*blo + ghi_s[rr]*bhi;
          out[(size_t)grow*DM + n] = bf2f(f2bf(v));
        }
      }
    }
  }
}

extern "C" void kernel_launch(void* const* d_in, const int* in_sizes, int n_in,
                              void* d_out, int out_size, void* d_ws, size_t ws_size,
                              hipStream_t stream){
  const float* x      = (const float*)d_in[0];
  const float* logits = (const float*)d_in[1];
  const int*   masks  = (const int*)d_in[2];
  const float* sel    = (const float*)d_in[3];
  const float* W      = (const float*)d_in[4];
  const float* bias   = (const float*)d_in[5];
  float* out = (float*)d_out;
  char* ws = (char*)d_ws;
  int*    counts  = (int*)(ws + WS_COUNTS);
  int*    count2  = (int*)(ws + WS_COUNT2);
  float*  sacc    = (float*)(ws + WS_SACC);
  int*    ntp     = (int*)(ws + WS_NT);
  int*    off     = (int*)(ws + WS_OFF);
  int4*   entries = (int4*)(ws + WS_ENT);
  int*    pidv    = (int*)(ws + WS_PID);
  float2* gatesb  = (float2*)(ws + WS_GATEB);
  int*    rows_s  = (int*)(ws + WS_ROWSS);
  unsigned short* wt = (unsigned short*)(ws + WS_WT);

  hipMemsetAsync(ws, 0, 640, stream);   // counts, count2, sacc, ntp
  cvtw_k<<<dim3(15, 8, 8), 256, 0, stream>>>(W, wt);
  gating_k<<<B_ROWS/4, 256, 0, stream>>>(logits, masks, sel, counts, sacc, pidv, gatesb, out);
  worklist_k<<<1, 64, 0, stream>>>(counts, off, ntp, entries, sacc, out);
  scatter_k<<<B_ROWS/256, 256, 0, stream>>>(pidv, off, count2, rows_s);
  gemm_k<<<dim3(MAXT, 4), 256, 0, stream>>>(x, wt, bias, ntp, entries, rows_s, gatesb, out);
}

// Round 6
// 327.594 us; speedup vs baseline: 1.6969x; 1.6969x over previous
//
#include <hip/hip_runtime.h>
#include <hip/hip_bf16.h>

// f32-uniform output buffer: final_out [B,512] (bf16-rounded f32),
// guide_loss f32 @ B*512, sel_emb [B,128] f32 @ B*512+1.
// B=16384, E=8, D_IN=900, D_MODEL=512, D_SEL=128, top-2.

#define B_ROWS 16384
#define DIN 900
#define DM 512
#define DSEL 128
#define KP 928
#define NKS 29
#define MAXT 192
#define EPSF 1e-9f

#define OUT_GUIDE (B_ROWS*DM)
#define OUT_SEL   (B_ROWS*DM + 1)

// workspace layout (bytes); total ~8.4 MB
#define WS_COUNTS 0                      // int[64]
#define WS_PART   512                    // float[64]
#define WS_NT     768                    // int
#define WS_OFF    1024                   // int[64]
#define WS_ENT    2048                   // int4[448]
#define WS_BB     9216                   // int[64*64] block bases
#define WS_PIDLR  25600                  // int[B]  pid | (lrank<<8)
#define WS_GATEB  91136                  // float2[B]
#define WS_W8     222208                 // float[B*8] inactive-mixture weights
#define WS_ROWSS  746496                 // int[B]
#define WS_WT     812032                 // ushort[E*DM*KP] (7.6 MB)

typedef __attribute__((ext_vector_type(8))) short short8;
typedef __attribute__((ext_vector_type(8))) unsigned short ushort8;
typedef __attribute__((ext_vector_type(4))) float floatx4;

__device__ inline unsigned short f2bf(float v){
  union { __hip_bfloat16 h; unsigned short u; } c;
  c.h = __float2bfloat16(v);
  return c.u;
}
__device__ inline float bf2f(unsigned short u){
  union { unsigned int i; float f; } c;
  c.i = ((unsigned int)u) << 16;
  return c.f;
}

// ---- W f32 [E,900,512] -> bf16 transposed [E,512,928] (K zero-padded) ----
__global__ __launch_bounds__(256) void cvtw_k(const float* __restrict__ W,
                                              unsigned short* __restrict__ wt){
  __shared__ unsigned short tl[64][65];
  int kt = blockIdx.x, ntb = blockIdx.y, e = blockIdx.z;
  int c = threadIdx.x & 63, q = threadIdx.x >> 6;
  for (int i = 0; i < 16; i++){
    int kl = q + i*4;
    int k = kt*64 + kl;
    float v = (k < DIN) ? W[((size_t)e*DIN + k)*DM + ntb*64 + c] : 0.f;
    tl[kl][c] = f2bf(v);
  }
  __syncthreads();
  for (int i = 0; i < 16; i++){
    int nl = q + i*4;
    int k = kt*64 + c;
    if (k < KP)
      wt[((size_t)e*DM + ntb*64 + nl)*KP + k] = tl[c][nl];
  }
}

// ---- gating: thread-per-row; no hot atomics ----
__global__ __launch_bounds__(256) void gating_k(const float* __restrict__ logits,
                                                const int* __restrict__ masks,
                                                int* __restrict__ counts,
                                                float* __restrict__ partials,
                                                int* __restrict__ pidlr,
                                                float2* __restrict__ gatesb,
                                                float* __restrict__ w8,
                                                int* __restrict__ blockbase){
  __shared__ int hist[64];
  __shared__ float wsum[4];
  int t = threadIdx.x;
  if (t < 64) hist[t] = 0;
  __syncthreads();
  int b = blockIdx.x*256 + t;
  float4 l0 = *(const float4*)&logits[(size_t)b*8];
  float4 l1 = *(const float4*)&logits[(size_t)b*8 + 4];
  int4  m0 = *(const int4*)&masks[(size_t)b*8];
  int4  m1 = *(const int4*)&masks[(size_t)b*8 + 4];
  float raw[8] = {l0.x,l0.y,l0.z,l0.w,l1.x,l1.y,l1.z,l1.w};
  int   mk[8]  = {m0.x,m0.y,m0.z,m0.w,m1.x,m1.y,m1.z,m1.w};
  float mx = raw[0];
  for (int e = 1; e < 8; e++) mx = fmaxf(mx, raw[e]);
  float Z = 0.f;
  for (int e = 0; e < 8; e++){ raw[e] = expf(raw[e]-mx); Z += raw[e]; }
  float invZ = 1.f/Z;
  float act[8], ina[8]; float srm = 0.f, isum = 0.f;
  for (int e = 0; e < 8; e++){
    raw[e] *= invZ;
    if (mk[e] == 1){ act[e] = raw[e]; ina[e] = 0.f; srm += raw[e]; }
    else           { act[e] = 0.f;    ina[e] = raw[e]; isum += raw[e]; }
  }
  float v1 = -1.f, v2 = -1.f; int e1 = 0, e2 = 0;
  for (int e = 0; e < 8; e++){
    float a = act[e];
    if (a > v1){ v2 = v1; e2 = e1; v1 = a; e1 = e; }
    else if (a > v2){ v2 = a; e2 = e; }
  }
  float den = v1 + v2 + EPSF;
  float g1 = v1/den, g2 = v2/den;
  int lo, hi; float gl, gh;
  if (e1 < e2){ lo = e1; hi = e2; gl = g1; gh = g2; }
  else        { lo = e2; hi = e1; gl = g2; gh = g1; }
  int pid = lo*8 + hi;
  float invI = 1.f/(isum + EPSF);
  for (int e = 0; e < 8; e++) w8[(size_t)b*8 + e] = ina[e]*invI;
  gatesb[b] = make_float2(gl, gh);
  int lr = atomicAdd(&hist[pid], 1);     // LDS atomic: local rank
  pidlr[b] = pid | (lr << 8);
  // block reduce srm -> partials[blockIdx]
  float s = srm;
  for (int sft = 32; sft > 0; sft >>= 1) s += __shfl_down(s, sft, 64);
  if ((t & 63) == 0) wsum[t >> 6] = s;
  __syncthreads();
  if (t < 64){
    int c = hist[t];
    int base = 0;
    if (c > 0) base = atomicAdd(&counts[t], c);   // <=64 atomics/block
    blockbase[blockIdx.x*64 + t] = base;
  }
  if (t == 0) partials[blockIdx.x] = wsum[0] + wsum[1] + wsum[2] + wsum[3];
}

// ---- selection embedding: coalesced, 2 rows per block ----
__global__ __launch_bounds__(256) void selemb_k(const float* __restrict__ sel,
                                                const float* __restrict__ w8,
                                                float* __restrict__ out){
  int t = threadIdx.x;
  int b = blockIdx.x*2 + (t >> 7);
  int d = t & 127;
  const float* wr = w8 + (size_t)b*8;
  const float* sb = sel + (size_t)b*(8*DSEL);
  float a = 0.f;
  for (int e = 0; e < 8; e++) a += wr[e] * sb[e*DSEL + d];
  out[OUT_SEL + (size_t)b*DSEL + d] = a;
}

// ---- worklist: one 64-lane wave; shuffle scans; guide loss ----
__global__ void worklist_k(const int* __restrict__ counts,
                           const float* __restrict__ partials,
                           int* __restrict__ off, int* __restrict__ ntp,
                           int4* __restrict__ entries,
                           float* __restrict__ out){
  int lane = threadIdx.x;      // 64 threads
  int c = counts[lane];
  int sc = c;
  for (int s = 1; s < 64; s <<= 1){ int v = __shfl_up(sc, s, 64); if (lane >= s) sc += v; }
  int offp = sc - c;
  off[lane] = offp;
  int nt = (c + 127) >> 7;
  int snt = nt;
  for (int s = 1; s < 64; s <<= 1){ int v = __shfl_up(snt, s, 64); if (lane >= s) snt += v; }
  int tbase = snt - nt;
  int elo = lane >> 3, ehi = lane & 7;
  for (int j = 0; j < nt; ++j){
    int nr = c - j*128; if (nr > 128) nr = 128;
    entries[tbase + j] = make_int4(elo, ehi, offp + j*128, nr);
  }
  int tot = __shfl(snt, 63, 64);
  if (lane == 0) *ntp = tot;
  float p = partials[lane];
  for (int s = 32; s > 0; s >>= 1) p += __shfl_down(p, s, 64);
  if (lane == 0){
    float sv = p * (1.f/B_ROWS);
    float d = 1.f - sv;
    out[OUT_GUIDE] = d*d;
  }
}

// ---- scatter: pure computed store, no atomics ----
__global__ __launch_bounds__(256) void scatter_k(const int* __restrict__ pidlr,
                                                 const int* __restrict__ off,
                                                 const int* __restrict__ blockbase,
                                                 int* __restrict__ rows_s){
  int b = blockIdx.x*256 + threadIdx.x;
  int pl = pidlr[b];
  int p = pl & 255; p &= 63;
  int lr = pl >> 8;
  rows_s[off[p] + blockbase[(b >> 8)*64 + p] + lr] = b;
}

// ---- grouped GEMM: unchanged from round 5 ----
__global__ __launch_bounds__(256) void gemm_k(const float* __restrict__ xf,
                                              const unsigned short* __restrict__ wt,
                                              const float* __restrict__ bias,
                                              const int* __restrict__ ntp,
                                              const int4* __restrict__ entries,
                                              const int* __restrict__ rows_s,
                                              const float2* __restrict__ gatesb,
                                              float* __restrict__ out){
  int tile = blockIdx.x;
  if (tile >= *ntp) return;
  int4 ent = entries[tile];
  int elo = ent.x, ehi = ent.y, start = ent.z, nrows = ent.w;

  __shared__ __align__(16) unsigned short xs[128*40];
  __shared__ int   gidx_s[128];
  __shared__ float glo_s[128];
  __shared__ float ghi_s[128];

  int t = threadIdx.x;
  if (t < 128){
    if (t < nrows){
      int g = rows_s[start + t];
      gidx_s[t] = g;
      float2 gg = gatesb[g];
      glo_s[t] = gg.x; ghi_s[t] = gg.y;
    } else { gidx_s[t] = -1; glo_s[t] = 0.f; ghi_s[t] = 0.f; }
  }
  __syncthreads();

  int lane = t & 63, wid = t >> 6;
  int wrow = wid >> 1, wcol = wid & 1;
  int quad = lane >> 4, l16 = lane & 15;
  int colbase = blockIdx.y*128 + wcol*64;

  int srow = t >> 1, skc = t & 1;
  int sg = gidx_s[srow];
  const float* xrow = xf + (size_t)(sg >= 0 ? sg : 0)*DIN + skc*16;

  floatx4 acc[4][4];
  for (int i = 0; i < 4; i++) for (int j = 0; j < 4; j++)
    for (int r = 0; r < 4; r++) acc[i][j][r] = 0.f;

  for (int pass = 0; pass < 2; ++pass){
    int e = pass ? ehi : elo;
    float g = (sg >= 0) ? (pass ? ghi_s[srow] : glo_s[srow]) : 0.f;
    const unsigned short* wb = wt + (size_t)e*DM*KP;
    for (int ks = 0; ks < NKS; ++ks){
      __syncthreads();
      ushort8 y0, y1;
      if (ks < 28){
        const float4* p = (const float4*)(xrow + ks*32);
        float4 a0 = p[0], a1 = p[1], a2 = p[2], a3 = p[3];
        y0[0]=f2bf(g*a0.x); y0[1]=f2bf(g*a0.y); y0[2]=f2bf(g*a0.z); y0[3]=f2bf(g*a0.w);
        y0[4]=f2bf(g*a1.x); y0[5]=f2bf(g*a1.y); y0[6]=f2bf(g*a1.z); y0[7]=f2bf(g*a1.w);
        y1[0]=f2bf(g*a2.x); y1[1]=f2bf(g*a2.y); y1[2]=f2bf(g*a2.z); y1[3]=f2bf(g*a2.w);
        y1[4]=f2bf(g*a3.x); y1[5]=f2bf(g*a3.y); y1[6]=f2bf(g*a3.z); y1[7]=f2bf(g*a3.w);
      } else {
        for (int j = 0; j < 8; j++){
          int k = ks*32 + skc*16 + j;
          float v = (k < DIN) ? xrow[ks*32 + j] : 0.f;
          y0[j] = f2bf(g*v);
        }
        for (int j = 0; j < 8; j++){
          int k = ks*32 + skc*16 + 8 + j;
          float v = (k < DIN) ? xrow[ks*32 + 8 + j] : 0.f;
          y1[j] = f2bf(g*v);
        }
      }
      *((ushort8*)&xs[srow*40 + skc*16])     = y0;
      *((ushort8*)&xs[srow*40 + skc*16 + 8]) = y1;
      __syncthreads();
      short8 af[4];
      for (int mt = 0; mt < 4; ++mt)
        af[mt] = *((const short8*)&xs[(wrow*64 + mt*16 + l16)*40 + quad*8]);
      for (int nt = 0; nt < 4; ++nt){
        int n = colbase + nt*16 + l16;
        short8 bfr = *((const short8*)(wb + (size_t)n*KP + ks*32 + quad*8));
        for (int mt = 0; mt < 4; ++mt)
          acc[mt][nt] = __builtin_amdgcn_mfma_f32_16x16x32_bf16(af[mt], bfr, acc[mt][nt], 0, 0, 0);
      }
    }
  }
  for (int nt = 0; nt < 4; ++nt){
    int n = colbase + nt*16 + l16;
    float blo = bias[elo*DM + n];
    float bhi = bias[ehi*DM + n];
    for (int mt = 0; mt < 4; ++mt){
      int rl = wrow*64 + mt*16 + quad*4;
      for (int r = 0; r < 4; ++r){
        int rr = rl + r;
        int grow = gidx_s[rr];
        if (grow >= 0){
          float v = acc[mt][nt][r] + glo_s[rr]*blo + ghi_s[rr]*bhi;
          out[(size_t)grow*DM + n] = bf2f(f2bf(v));
        }
      }
    }
  }
}

extern "C" void kernel_launch(void* const* d_in, const int* in_sizes, int n_in,
                              void* d_out, int out_size, void* d_ws, size_t ws_size,
                              hipStream_t stream){
  const float* x      = (const float*)d_in[0];
  const float* logits = (const float*)d_in[1];
  const int*   masks  = (const int*)d_in[2];
  const float* sel    = (const float*)d_in[3];
  const float* W      = (const float*)d_in[4];
  const float* bias   = (const float*)d_in[5];
  float* out = (float*)d_out;
  char* ws = (char*)d_ws;
  int*    counts   = (int*)(ws + WS_COUNTS);
  float*  partials = (float*)(ws + WS_PART);
  int*    ntp      = (int*)(ws + WS_NT);
  int*    off      = (int*)(ws + WS_OFF);
  int4*   entries  = (int4*)(ws + WS_ENT);
  int*    blockbase= (int*)(ws + WS_BB);
  int*    pidlr    = (int*)(ws + WS_PIDLR);
  float2* gatesb   = (float2*)(ws + WS_GATEB);
  float*  w8       = (float*)(ws + WS_W8);
  int*    rows_s   = (int*)(ws + WS_ROWSS);
  unsigned short* wt = (unsigned short*)(ws + WS_WT);

  hipMemsetAsync(ws, 0, 256, stream);   // counts
  cvtw_k<<<dim3(15, 8, 8), 256, 0, stream>>>(W, wt);
  gating_k<<<B_ROWS/256, 256, 0, stream>>>(logits, masks, counts, partials, pidlr, gatesb, w8, blockbase);
  worklist_k<<<1, 64, 0, stream>>>(counts, partials, off, ntp, entries, out);
  scatter_k<<<B_ROWS/256, 256, 0, stream>>>(pidlr, off, blockbase, rows_s);
  selemb_k<<<B_ROWS/2, 256, 0, stream>>>(sel, w8, out);
  gemm_k<<<dim3(MAXT, 4), 256, 0, stream>>>(x, wt, bias, ntp, entries, rows_s, gatesb, out);
}